// Round 3
// baseline (478.318 us; speedup 1.0000x reference)
//
#include <hip/hip_runtime.h>

typedef __attribute__((ext_vector_type(8))) short bh8;
typedef __attribute__((ext_vector_type(4))) float f4;

#define DEVI static __device__ __forceinline__

DEVI unsigned short f2b(float f) {
  union { float f; unsigned u; } v; v.f = f;
  unsigned r = v.u + 0x7fffu + ((v.u >> 16) & 1u);
  return (unsigned short)(r >> 16);
}
DEVI float b2f(unsigned short h) {
  union { unsigned u; float f; } v; v.u = ((unsigned)h) << 16;
  return v.f;
}
DEVI f4 mfma16(bh8 a, bh8 b, f4 c) {
  return __builtin_amdgcn_mfma_f32_16x16x32_bf16(a, b, c, 0, 0, 0);
}
DEVI void gload_lds16(const unsigned short* g, unsigned short* l) {
  __builtin_amdgcn_global_load_lds(
      (const __attribute__((address_space(1))) void*)(g),
      (__attribute__((address_space(3))) void*)(l), 16, 0, 0);
}

// ============================ prep kernels ============================
__global__ __launch_bounds__(256) void prep_x_kern(
    const float* __restrict__ q, const float* __restrict__ k, const float* __restrict__ v,
    unsigned short* __restrict__ xq, unsigned short* __restrict__ xk, unsigned short* __restrict__ xv) {
  long i = ((long)blockIdx.x * 256 + threadIdx.x) * 4;
  if (i >= 8388608L) return;
  float4 a = *(const float4*)(q + i);
  float4 b = *(const float4*)(k + i);
  float4 c = *(const float4*)(v + i);
  union { unsigned short s[4]; uint2 u; } pa, pb, pc;
  pa.s[0] = f2b(a.x); pa.s[1] = f2b(a.y); pa.s[2] = f2b(a.z); pa.s[3] = f2b(a.w);
  pb.s[0] = f2b(b.x); pb.s[1] = f2b(b.y); pb.s[2] = f2b(b.z); pb.s[3] = f2b(b.w);
  pc.s[0] = f2b(c.x); pc.s[1] = f2b(c.y); pc.s[2] = f2b(c.z); pc.s[3] = f2b(c.w);
  *(uint2*)(xq + i) = pa.u;
  *(uint2*)(xk + i) = pb.u;
  *(uint2*)(xv + i) = pc.u;
}

__global__ __launch_bounds__(256) void prep_w_kern(
    const float* __restrict__ wq, const float* __restrict__ wk, const float* __restrict__ wv,
    const float* __restrict__ g_in_w, const float* __restrict__ g_out_w,
    const float* __restrict__ wo, const float* __restrict__ rel_k,
    unsigned short* __restrict__ Wq, unsigned short* __restrict__ Wk, unsigned short* __restrict__ Wv,
    unsigned short* __restrict__ Wgo, unsigned short* __restrict__ Wo_, unsigned short* __restrict__ Rk) {
  long i = ((long)blockIdx.x * 256 + threadIdx.x) * 4;
  if (i >= 2129984L) return;
  const float* src; unsigned short* dst; long off;
  if (i < 524288L)        { dst = Wq;  off = i; src = (i < 262144L) ? wq + i : g_in_w + (i - 262144L); }
  else if (i < 1048576L)  { long j = i - 524288L;  dst = Wk;  off = j; src = (j < 262144L) ? wk + j : g_in_w + j; }
  else if (i < 1572864L)  { long j = i - 1048576L; dst = Wv;  off = j; src = (j < 262144L) ? wv + j : g_in_w + 262144L + j; }
  else if (i < 1835008L)  { long j = i - 1572864L; dst = Wgo; off = j; src = g_out_w + j; }
  else if (i < 2097152L)  { long j = i - 1835008L; dst = Wo_; off = j; src = wo + j; }
  else                    { long j = i - 2097152L; dst = Rk;  off = j; src = rel_k + j; }
  float4 f = *(const float4*)src;
  union { unsigned short s[4]; uint2 u; } p;
  p.s[0] = f2b(f.x); p.s[1] = f2b(f.y); p.s[2] = f2b(f.z); p.s[3] = f2b(f.w);
  *(uint2*)(dst + off) = p.u;
}

// ============================ GEMM ============================
// C[row,col] = sum_k A[row,k]*Bw[col,k] (+bias); A:[M,512], Bw:[N,512] bf16.
// Double-buffered LDS, one barrier per k-step, chunk-XOR swizzle (2-way max).
template <int NB, int EPI>
__global__ __launch_bounds__(256) void gemm_bf16_kern(
    const unsigned short* __restrict__ A, const unsigned short* __restrict__ Bw,
    const float* __restrict__ bias0, const float* __restrict__ bias1,
    const unsigned short* __restrict__ aux,
    unsigned short* __restrict__ outb, unsigned short* __restrict__ outb2,
    float* __restrict__ outf) {
  __shared__ unsigned short lsA[2][4096];
  __shared__ unsigned short lsB[2][4096];
  const int t = threadIdx.x;
  const int lane = t & 63, w = t >> 6;
  const int l15 = lane & 15, g = lane >> 4, g4 = g * 4;
  const int gs8 = (g ^ ((l15 >> 1) & 3)) * 8;   // swizzled read chunk
  int n = blockIdx.x;
  int x = n >> 3, c = n & 7;
  const int rb = (c * 16 + (x & 15)) * 128;
  const int cb = (x >> 4) * 128;
  const int wr = (w >> 1) * 64, wc = (w & 1) * 64;
  // staging: thread t fills LDS linear slots t*8 and 2048+t*8 (u16).
  // linear slot (row r, chunk c=t&3) must hold global k-chunk c ^ ((r>>1)&3).
  const int r0 = t >> 2, r1 = 64 + (t >> 2);
  const int k0i = (((t & 3) ^ ((t >> 3) & 3)) * 8);  // same for r0 and r1
  const unsigned short* pa0 = A + (long)(rb + r0) * 512 + k0i;
  const unsigned short* pa1 = A + (long)(rb + r1) * 512 + k0i;
  const unsigned short* pb0 = Bw + (long)(cb + r0) * 512 + k0i;
  const unsigned short* pb1 = Bw + (long)(cb + r1) * 512 + k0i;

#define STAGE(KK, BUF) { \
    gload_lds16(pa0 + (KK), lsA[BUF] + w * 512); \
    gload_lds16(pa1 + (KK), lsA[BUF] + 2048 + w * 512); \
    gload_lds16(pb0 + (KK), lsB[BUF] + w * 512); \
    gload_lds16(pb1 + (KK), lsB[BUF] + 2048 + w * 512); }

  STAGE(0, 0);
  asm volatile("s_waitcnt vmcnt(0)" ::: "memory");
  __builtin_amdgcn_s_barrier();
  __builtin_amdgcn_sched_barrier(0);

  f4 acc[4][4] = {};
  int cur = 0;
  for (int kk = 0; kk < 512; kk += 32) {
    bh8 af[4], bf[4];
#pragma unroll
    for (int m = 0; m < 4; m++) af[m] = *(const bh8*)(lsA[cur] + (wr + m * 16 + l15) * 32 + gs8);
#pragma unroll
    for (int nn = 0; nn < 4; nn++) bf[nn] = *(const bh8*)(lsB[cur] + (wc + nn * 16 + l15) * 32 + gs8);
    if (kk + 32 < 512) STAGE(kk + 32, cur ^ 1);
    __builtin_amdgcn_s_setprio(1);
#pragma unroll
    for (int m = 0; m < 4; m++)
#pragma unroll
      for (int nn = 0; nn < 4; nn++)
        acc[m][nn] = mfma16(af[m], bf[nn], acc[m][nn]);
    __builtin_amdgcn_s_setprio(0);
    __builtin_amdgcn_sched_barrier(0);
    asm volatile("s_waitcnt vmcnt(0) lgkmcnt(0)" ::: "memory");
    __builtin_amdgcn_s_barrier();
    __builtin_amdgcn_sched_barrier(0);
    cur ^= 1;
  }
#undef STAGE

#pragma unroll
  for (int m = 0; m < 4; m++) {
#pragma unroll
    for (int nn = 0; nn < 4; nn++) {
#pragma unroll
      for (int j = 0; j < 4; j++) {
        int row = rb + wr + m * 16 + g4 + j;
        int col = cb + wc + nn * 16 + l15;
        float v = acc[m][nn][j];
        if constexpr (EPI == 0) {
          v += (col < 512) ? bias0[col] : bias1[col - 512];
          outb[(long)row * (NB * 128) + col] = f2b(v);
        } else if constexpr (EPI == 3) {
          v += (col < 512) ? bias0[col] : bias1[col - 512];
          int b = row >> 9, s = row & 511;
          if (col < 512) {
            int h = col >> 6, d = col & 63;
            outb[(((long)(b * 8 + h) * 64 + d) << 9) + s] = f2b(v);
          } else {
            int c2 = col - 512, hg = c2 >> 7, dg = c2 & 127;
            outb2[(((long)(b * 4 + hg) * 128 + dg) << 9) + s] = f2b(v);
          }
        } else if constexpr (EPI == 1) {
          v += bias0[col];
          float cv = 0.7f * b2f(aux[(long)row * 512 + col]) + 0.3f * v;
          outb[(long)row * 512 + col] = f2b(cv);
        } else {
          v += bias0[col];
          outf[(long)row * 512 + col] = v;
        }
      }
    }
  }
}

// ============================ local attention ============================
// Row stride 524 u16: 2-way max bank aliasing on scalar gather/writes and b64 reads.
__global__ __launch_bounds__(256) void attn_local_kern(
    const unsigned short* __restrict__ Yq, const unsigned short* __restrict__ Yk,
    const unsigned short* __restrict__ Yvt, const unsigned short* __restrict__ relk,
    unsigned short* __restrict__ outL) {
  __shared__ unsigned short buf[16 * 524];
  __shared__ float redbuf[4][16];

  const int t = threadIdx.x, lane = t & 63, w = t >> 6;
  const int l15 = lane & 15, g = lane >> 4, g8 = g * 8;
  int n = blockIdx.x;
  int bid = (n & 7) * 1024 + (n >> 3);           // XCD swizzle
  const int qt = bid & 31;
  const int h = (bid >> 5) & 7;
  const int b = bid >> 8;
  const int qb = qt * 16;
  const long base = ((long)(b * 512)) * 1024 + h * 64;

  bh8 qf[2];
  {
    const unsigned short* qp = Yq + base + (long)(qb + l15) * 1024 + g8;
    qf[0] = *(const bh8*)(qp);
    qf[1] = *(const bh8*)(qp + 32);
  }

  // qrel = (Q @ relk^T) * LOG2E  -> buf rows [16][524]
  for (int tt = w; tt < 33; tt += 4) {
    f4 a = {};
    int ri = tt * 16 + l15; if (ri > 512) ri = 512;
    const unsigned short* rp = relk + ri * 64 + g8;
    a = mfma16(qf[0], *(const bh8*)(rp), a);
    a = mfma16(qf[1], *(const bh8*)(rp + 32), a);
    int col = tt * 16 + l15;
    if (col < 524) {
#pragma unroll
      for (int j = 0; j < 4; j++) buf[(g * 4 + j) * 524 + col] = f2b(a[j] * 1.4426950408889634f);
    }
  }

  // scores: wave w -> cols [w*128, w*128+128)
  f4 sc[8];
  __builtin_amdgcn_s_setprio(1);
#pragma unroll
  for (int ct = 0; ct < 8; ct++) {
    f4 a = {};
    int r = w * 128 + ct * 16 + l15;
    const unsigned short* kp = Yk + base + (long)r * 1024 + g8;
    a = mfma16(qf[0], *(const bh8*)(kp), a);
    a = mfma16(qf[1], *(const bh8*)(kp + 32), a);
    sc[ct] = a;
  }
  __builtin_amdgcn_s_setprio(0);
  __syncthreads();  // qrel visible

  // bias gather (clamped linear address) + exp2 + partial row-sums
#pragma unroll
  for (int j = 0; j < 4; j++) {
    int lrow = g * 4 + j;
    int rowb = lrow * 524;
    int a0 = rowb + 256 - (qb + lrow) + w * 128 + l15;
    int lo = rowb, hi = rowb + 512;
    float s = 0.f;
#pragma unroll
    for (int ct = 0; ct < 8; ct++) {
      int idx = a0 + ct * 16;
      idx = idx < lo ? lo : idx;
      idx = idx > hi ? hi : idx;
      float p = exp2f(fmaf(sc[ct][j], 0.18033688011112042f, b2f(buf[idx])));
      sc[ct][j] = p;
      s += p;
    }
    for (int d = 1; d < 16; d <<= 1) s += __shfl_xor(s, d, 64);
    if (l15 == 0) redbuf[w][lrow] = s;
  }
  __syncthreads();  // all qrel reads done + redbuf ready

  // probs into buf (reuse), gather total sums
#pragma unroll
  for (int ct = 0; ct < 8; ct++) {
    int col = w * 128 + ct * 16 + l15;
#pragma unroll
    for (int j = 0; j < 4; j++) buf[(g * 4 + j) * 524 + col] = f2b(sc[ct][j]);
  }
  float rinv[4];
#pragma unroll
  for (int j = 0; j < 4; j++) {
    int lrow = g * 4 + j;
    rinv[j] = __builtin_amdgcn_rcpf(redbuf[0][lrow] + redbuf[1][lrow] + redbuf[2][lrow] + redbuf[3][lrow]);
  }
  __syncthreads();  // probs visible

  // PV: probs[16,512] @ V[512,64]; wave w owns d-cols [w*16, w*16+16)
  f4 accO = {};
  const unsigned short* vrow = Yvt + ((long)(b * 8 + h) * 64 + w * 16 + l15) * 512;
  __builtin_amdgcn_s_setprio(1);
#pragma unroll
  for (int ks = 0; ks < 16; ks++) {
    union { uint2 u[2]; bh8 v; } pa;
    const unsigned short* pp = buf + l15 * 524 + ks * 32 + g8;
    pa.u[0] = *(const uint2*)(pp);
    pa.u[1] = *(const uint2*)(pp + 4);
    bh8 vb = *(const bh8*)(vrow + ks * 32 + g8);
    accO = mfma16(pa.v, vb, accO);
  }
  __builtin_amdgcn_s_setprio(0);
#pragma unroll
  for (int j = 0; j < 4; j++) {
    int row = qb + g * 4 + j;
    outL[((long)(b * 512 + row)) * 512 + h * 64 + w * 16 + l15] = f2b(accO[j] * rinv[j]);
  }
}

// ============================ global attention ============================
__global__ __launch_bounds__(256) void attn_glob_kern(
    const unsigned short* __restrict__ Yq, const unsigned short* __restrict__ Yk,
    const unsigned short* __restrict__ Yvt, unsigned short* __restrict__ outG) {
  __shared__ unsigned short buf[16 * 524];
  __shared__ float redbuf[4][16];

  const int t = threadIdx.x, lane = t & 63, w = t >> 6;
  const int l15 = lane & 15, g = lane >> 4, g8 = g * 8;
  int n = blockIdx.x;
  int bid = (n & 7) * 512 + (n >> 3);
  const int qt = bid & 31;
  const int hg = (bid >> 5) & 3;
  const int b = bid >> 7;
  const int qb = qt * 16;
  const long base = ((long)(b * 512)) * 1024 + 512 + hg * 128;

  bh8 qf[4];
  {
    const unsigned short* qp = Yq + base + (long)(qb + l15) * 1024 + g8;
#pragma unroll
    for (int ks = 0; ks < 4; ks++) qf[ks] = *(const bh8*)(qp + ks * 32);
  }

  f4 sc[8];
  __builtin_amdgcn_s_setprio(1);
#pragma unroll
  for (int ct = 0; ct < 8; ct++) {
    f4 a = {};
    int r = w * 128 + ct * 16 + l15;
    const unsigned short* kp = Yk + base + (long)r * 1024 + g8;
#pragma unroll
    for (int ks = 0; ks < 4; ks++) a = mfma16(qf[ks], *(const bh8*)(kp + ks * 32), a);
    sc[ct] = a;
  }
  __builtin_amdgcn_s_setprio(0);

#pragma unroll
  for (int j = 0; j < 4; j++) {
    int lrow = g * 4 + j;
    float s = 0.f;
#pragma unroll
    for (int ct = 0; ct < 8; ct++) {
      float p = exp2f(sc[ct][j] * 0.12751745334f);  // 1/sqrt(128) * log2(e)
      sc[ct][j] = p;
      s += p;
    }
    for (int d = 1; d < 16; d <<= 1) s += __shfl_xor(s, d, 64);
    if (l15 == 0) redbuf[w][lrow] = s;
  }
#pragma unroll
  for (int ct = 0; ct < 8; ct++) {
    int col = w * 128 + ct * 16 + l15;
#pragma unroll
    for (int j = 0; j < 4; j++) buf[(g * 4 + j) * 524 + col] = f2b(sc[ct][j]);
  }
  __syncthreads();  // probs + redbuf visible

  float rinv[4];
#pragma unroll
  for (int j = 0; j < 4; j++) {
    int lrow = g * 4 + j;
    rinv[j] = __builtin_amdgcn_rcpf(redbuf[0][lrow] + redbuf[1][lrow] + redbuf[2][lrow] + redbuf[3][lrow]);
  }

  // PV: out [16,128]; wave w owns d-tiles {w, w+4}
  f4 accO[2] = {};
  __builtin_amdgcn_s_setprio(1);
#pragma unroll
  for (int ks = 0; ks < 16; ks++) {
    union { uint2 u[2]; bh8 v; } pa;
    const unsigned short* pp = buf + l15 * 524 + ks * 32 + g8;
    pa.u[0] = *(const uint2*)(pp);
    pa.u[1] = *(const uint2*)(pp + 4);
#pragma unroll
    for (int m = 0; m < 2; m++) {
      int dt = w + m * 4;
      bh8 vb = *(const bh8*)(Yvt + ((long)(b * 4 + hg) * 128 + dt * 16 + l15) * 512 + ks * 32 + g8);
      accO[m] = mfma16(pa.v, vb, accO[m]);
    }
  }
  __builtin_amdgcn_s_setprio(0);
#pragma unroll
  for (int m = 0; m < 2; m++)
#pragma unroll
    for (int j = 0; j < 4; j++) {
      int row = qb + g * 4 + j;
      outG[((long)(b * 512 + row)) * 512 + hg * 128 + (w + m * 4) * 16 + l15] = f2b(accO[m][j] * rinv[j]);
    }
}

// ============================ launch ============================
extern "C" void kernel_launch(void* const* d_in, const int* in_sizes, int n_in,
                              void* d_out, int out_size, void* d_ws, size_t ws_size,
                              hipStream_t stream) {
  const float* query = (const float*)d_in[0];
  const float* key   = (const float*)d_in[1];
  const float* value = (const float*)d_in[2];
  const float* wq = (const float*)d_in[3];   const float* bq = (const float*)d_in[4];
  const float* wk = (const float*)d_in[5];   const float* bk = (const float*)d_in[6];
  const float* wv = (const float*)d_in[7];   const float* bv = (const float*)d_in[8];
  const float* wo = (const float*)d_in[9];   const float* bo = (const float*)d_in[10];
  const float* rel_k = (const float*)d_in[11];
  const float* g_in_w = (const float*)d_in[12];  const float* g_in_b = (const float*)d_in[13];
  const float* g_out_w = (const float*)d_in[14]; const float* g_out_b = (const float*)d_in[15];

  unsigned short* p = (unsigned short*)d_ws;
  unsigned short* Xq = p;            p += 8388608;
  unsigned short* Xk = p;            p += 8388608;
  unsigned short* Xv = p;            p += 8388608;
  unsigned short* Yq = p;            p += 16777216;   // [16384][1024]
  unsigned short* Yk = p;            p += 16777216;
  unsigned short* Yvt_l = p;         p += 8388608;    // [b][h][64][512]
  unsigned short* Yvt_g = p;         p += 8388608;    // [b][hg][128][512]
  unsigned short* Wq = p;            p += 524288;
  unsigned short* Wk = p;            p += 524288;
  unsigned short* Wv = p;            p += 524288;
  unsigned short* Wgo = p;           p += 262144;
  unsigned short* Wo_ = p;           p += 262144;
  unsigned short* Rk = p;            p += 32832;
  unsigned short* localb = Xq;
  unsigned short* gattnb = Xk;
  unsigned short* comb   = Xv;

  prep_x_kern<<<8192, 256, 0, stream>>>(query, key, value, Xq, Xk, Xv);
  prep_w_kern<<<2081, 256, 0, stream>>>(wq, wk, wv, g_in_w, g_out_w, wo, rel_k,
                                        Wq, Wk, Wv, Wgo, Wo_, Rk);

  gemm_bf16_kern<8, 0><<<1024, 256, 0, stream>>>(Xq, Wq, bq, g_in_b, nullptr, Yq, nullptr, nullptr);
  gemm_bf16_kern<8, 0><<<1024, 256, 0, stream>>>(Xk, Wk, bk, g_in_b + 512, nullptr, Yk, nullptr, nullptr);
  gemm_bf16_kern<8, 3><<<1024, 256, 0, stream>>>(Xv, Wv, bv, g_in_b + 1024, nullptr, Yvt_l, Yvt_g, nullptr);

  attn_local_kern<<<8192, 256, 0, stream>>>(Yq, Yk, Yvt_l, Rk, localb);
  attn_glob_kern<<<4096, 256, 0, stream>>>(Yq, Yk, Yvt_g, gattnb);

  gemm_bf16_kern<4, 1><<<512, 256, 0, stream>>>(gattnb, Wgo, g_out_b, nullptr, localb, comb, nullptr, nullptr);
  gemm_bf16_kern<4, 2><<<512, 256, 0, stream>>>(comb, Wo_, bo, nullptr, nullptr, nullptr, nullptr, (float*)d_out);
}

// Round 4
// 383.875 us; speedup vs baseline: 1.2460x; 1.2460x over previous
//
#include <hip/hip_runtime.h>

typedef __attribute__((ext_vector_type(8))) short bh8;
typedef __attribute__((ext_vector_type(4))) float f4;

#define DEVI static __device__ __forceinline__

DEVI unsigned short f2b(float f) {
  union { float f; unsigned u; } v; v.f = f;
  unsigned r = v.u + 0x7fffu + ((v.u >> 16) & 1u);
  return (unsigned short)(r >> 16);
}
DEVI float b2f(unsigned short h) {
  union { unsigned u; float f; } v; v.u = ((unsigned)h) << 16;
  return v.f;
}
DEVI f4 mfma16(bh8 a, bh8 b, f4 c) {
  return __builtin_amdgcn_mfma_f32_16x16x32_bf16(a, b, c, 0, 0, 0);
}
DEVI void gload_lds16(const unsigned short* g, unsigned short* l) {
  __builtin_amdgcn_global_load_lds(
      (const __attribute__((address_space(1))) void*)(g),
      (__attribute__((address_space(3))) void*)(l), 16, 0, 0);
}

// ============================ prep kernels ============================
__global__ __launch_bounds__(256) void prep_x_kern(
    const float* __restrict__ q, const float* __restrict__ k, const float* __restrict__ v,
    unsigned short* __restrict__ xq, unsigned short* __restrict__ xk, unsigned short* __restrict__ xv) {
  long i = ((long)blockIdx.x * 256 + threadIdx.x) * 4;
  if (i >= 8388608L) return;
  float4 a = *(const float4*)(q + i);
  float4 b = *(const float4*)(k + i);
  float4 c = *(const float4*)(v + i);
  union { unsigned short s[4]; uint2 u; } pa, pb, pc;
  pa.s[0] = f2b(a.x); pa.s[1] = f2b(a.y); pa.s[2] = f2b(a.z); pa.s[3] = f2b(a.w);
  pb.s[0] = f2b(b.x); pb.s[1] = f2b(b.y); pb.s[2] = f2b(b.z); pb.s[3] = f2b(b.w);
  pc.s[0] = f2b(c.x); pc.s[1] = f2b(c.y); pc.s[2] = f2b(c.z); pc.s[3] = f2b(c.w);
  *(uint2*)(xq + i) = pa.u;
  *(uint2*)(xk + i) = pb.u;
  *(uint2*)(xv + i) = pc.u;
}

__global__ __launch_bounds__(256) void prep_w_kern(
    const float* __restrict__ wq, const float* __restrict__ wk, const float* __restrict__ wv,
    const float* __restrict__ g_in_w, const float* __restrict__ g_out_w,
    const float* __restrict__ wo, const float* __restrict__ rel_k,
    unsigned short* __restrict__ Wq, unsigned short* __restrict__ Wk, unsigned short* __restrict__ Wv,
    unsigned short* __restrict__ Wgo, unsigned short* __restrict__ Wo_, unsigned short* __restrict__ Rk) {
  long i = ((long)blockIdx.x * 256 + threadIdx.x) * 4;
  if (i >= 2129984L) return;
  const float* src; unsigned short* dst; long off;
  if (i < 524288L)        { dst = Wq;  off = i; src = (i < 262144L) ? wq + i : g_in_w + (i - 262144L); }
  else if (i < 1048576L)  { long j = i - 524288L;  dst = Wk;  off = j; src = (j < 262144L) ? wk + j : g_in_w + j; }
  else if (i < 1572864L)  { long j = i - 1048576L; dst = Wv;  off = j; src = (j < 262144L) ? wv + j : g_in_w + 262144L + j; }
  else if (i < 1835008L)  { long j = i - 1572864L; dst = Wgo; off = j; src = g_out_w + j; }
  else if (i < 2097152L)  { long j = i - 1835008L; dst = Wo_; off = j; src = wo + j; }
  else                    { long j = i - 2097152L; dst = Rk;  off = j; src = rel_k + j; }
  float4 f = *(const float4*)src;
  union { unsigned short s[4]; uint2 u; } p;
  p.s[0] = f2b(f.x); p.s[1] = f2b(f.y); p.s[2] = f2b(f.z); p.s[3] = f2b(f.w);
  *(uint2*)(dst + off) = p.u;
}

// ============================ GEMM (R2 form) ============================
template <int NB, int EPI>
__global__ __launch_bounds__(256) void gemm_bf16_kern(
    const unsigned short* __restrict__ A, const unsigned short* __restrict__ Bw,
    const float* __restrict__ bias0, const float* __restrict__ bias1,
    const unsigned short* __restrict__ aux,
    unsigned short* __restrict__ outb, unsigned short* __restrict__ outb2,
    float* __restrict__ outf) {
  __shared__ unsigned short lsA[128 * 32];
  __shared__ unsigned short lsB[128 * 32];
  const int t = threadIdx.x;
  const int lane = t & 63, w = t >> 6;
  const int l15 = lane & 15, g8 = (lane >> 4) * 8, g4 = (lane >> 4) * 4;
  int n = blockIdx.x;
  int x = n >> 3, c = n & 7;
  const int rb = (c * 16 + (x & 15)) * 128;
  const int cb = (x >> 4) * 128;
  const int wr = (w >> 1) * 64, wc = (w & 1) * 64;
  const int e0 = t * 8, e1 = 2048 + t * 8;
  const int r0 = e0 >> 5, k0i = e0 & 31;
  const int r1 = e1 >> 5, k1i = e1 & 31;

  const unsigned short* pa0 = A + (long)(rb + r0) * 512 + k0i;
  const unsigned short* pa1 = A + (long)(rb + r1) * 512 + k1i;
  const unsigned short* pb0 = Bw + (long)(cb + r0) * 512 + k0i;
  const unsigned short* pb1 = Bw + (long)(cb + r1) * 512 + k1i;
  unsigned short* dA0 = lsA + w * 512;
  unsigned short* dA1 = lsA + 2048 + w * 512;
  unsigned short* dB0 = lsB + w * 512;
  unsigned short* dB1 = lsB + 2048 + w * 512;

  f4 acc[4][4] = {};
  for (int k0 = 0; k0 < 512; k0 += 32) {
    __syncthreads();
    gload_lds16(pa0 + k0, dA0);
    gload_lds16(pa1 + k0, dA1);
    gload_lds16(pb0 + k0, dB0);
    gload_lds16(pb1 + k0, dB1);
    __syncthreads();
    bh8 af[4], bf[4];
#pragma unroll
    for (int m = 0; m < 4; m++) af[m] = *(const bh8*)(lsA + (wr + m * 16 + l15) * 32 + g8);
#pragma unroll
    for (int nn = 0; nn < 4; nn++) bf[nn] = *(const bh8*)(lsB + (wc + nn * 16 + l15) * 32 + g8);
#pragma unroll
    for (int m = 0; m < 4; m++)
#pragma unroll
      for (int nn = 0; nn < 4; nn++)
        acc[m][nn] = mfma16(af[m], bf[nn], acc[m][nn]);
  }
#pragma unroll
  for (int m = 0; m < 4; m++) {
#pragma unroll
    for (int nn = 0; nn < 4; nn++) {
#pragma unroll
      for (int j = 0; j < 4; j++) {
        int row = rb + wr + m * 16 + g4 + j;
        int col = cb + wc + nn * 16 + l15;
        float v = acc[m][nn][j];
        if constexpr (EPI == 0) {
          v += (col < 512) ? bias0[col] : bias1[col - 512];
          outb[(long)row * (NB * 128) + col] = f2b(v);
        } else if constexpr (EPI == 3) {
          v += (col < 512) ? bias0[col] : bias1[col - 512];
          int b = row >> 9, s = row & 511;
          if (col < 512) {
            int h = col >> 6, d = col & 63;
            outb[(((long)(b * 8 + h) * 64 + d) << 9) + s] = f2b(v);
          } else {
            int c2 = col - 512, hg = c2 >> 7, dg = c2 & 127;
            outb2[(((long)(b * 4 + hg) * 128 + dg) << 9) + s] = f2b(v);
          }
        } else if constexpr (EPI == 1) {
          v += bias0[col];
          float cv = 0.7f * b2f(aux[(long)row * 512 + col]) + 0.3f * v;
          outb[(long)row * 512 + col] = f2b(cv);
        } else {
          v += bias0[col];
          outf[(long)row * 512 + col] = v;
        }
      }
    }
  }
}

// ============================ local attention v3 ============================
// Block = 32 q-rows, 8 waves. K [512][64] staged async into LDS (XOR-swizzled),
// region reused for V [64][512] after QK. buf holds qrel then probs.
__global__ __launch_bounds__(512) void attn_local_kern(
    const unsigned short* __restrict__ Yq, const unsigned short* __restrict__ Yk,
    const unsigned short* __restrict__ Yvt, const unsigned short* __restrict__ relk,
    unsigned short* __restrict__ outL) {
  __shared__ unsigned short kv[32768];      // 64KB: K [512][64] -> V [64][512]
  __shared__ unsigned short buf[32 * 524];  // qrel then probs
  __shared__ float redbuf[8][32];

  const int t = threadIdx.x, lane = t & 63, w = t >> 6;
  const int l15 = lane & 15, g = lane >> 4, g8 = g * 8;
  int n = blockIdx.x;
  int bid = (n & 7) * 512 + (n >> 3);       // XCD swizzle: 512 consecutive bids per XCD
  const int qt = bid & 15;
  const int h = (bid >> 4) & 7;
  const int b = bid >> 7;
  const int qb = qt * 32;
  const long base = ((long)(b * 512)) * 1024 + h * 64;
  const long vbase = ((long)(b * 8 + h)) * 64 * 512;

  // issue K stage: slot c holds global chunk c^(r&7); dest wave-linear
  {
    const int r = t >> 3, c = t & 7;
#pragma unroll
    for (int it = 0; it < 8; it++) {
      int rr = it * 64 + r;
      gload_lds16(Yk + base + (long)rr * 1024 + ((c ^ (rr & 7)) * 8), kv + it * 4096 + w * 512);
    }
  }

  // Q fragments: 2 m-tiles
  bh8 qf[2][2];
#pragma unroll
  for (int mm = 0; mm < 2; mm++) {
    const unsigned short* qp = Yq + base + (long)(qb + mm * 16 + l15) * 1024 + g8;
    qf[mm][0] = *(const bh8*)(qp);
    qf[mm][1] = *(const bh8*)(qp + 32);
  }

  // qrel = (Q @ relk^T)*LOG2E -> buf[32][524]   (overlaps K staging)
  for (int tt = w; tt < 33; tt += 8) {
    int ri = tt * 16 + l15; if (ri > 512) ri = 512;
    const unsigned short* rp = relk + ri * 64 + g8;
    bh8 rf0 = *(const bh8*)(rp), rf1 = *(const bh8*)(rp + 32);
    int col = tt * 16 + l15;
#pragma unroll
    for (int mm = 0; mm < 2; mm++) {
      f4 a = {};
      a = mfma16(qf[mm][0], rf0, a);
      a = mfma16(qf[mm][1], rf1, a);
      if (col < 524) {
#pragma unroll
        for (int j = 0; j < 4; j++)
          buf[(mm * 16 + g * 4 + j) * 524 + col] = f2b(a[j] * 1.4426950408889634f);
      }
    }
  }
  __syncthreads();  // B0: K staged + qrel visible

  // QK from LDS: wave w -> cols [w*64, w*64+64)
  f4 sc[2][4];
  __builtin_amdgcn_s_setprio(1);
#pragma unroll
  for (int ct = 0; ct < 4; ct++) {
    int r = w * 64 + ct * 16 + l15;
    int rb8 = r * 64;
    bh8 k0 = *(const bh8*)(kv + rb8 + ((g ^ (r & 7)) * 8));
    bh8 k1 = *(const bh8*)(kv + rb8 + (((g + 4) ^ (r & 7)) * 8));
#pragma unroll
    for (int mm = 0; mm < 2; mm++) {
      f4 a = {};
      a = mfma16(qf[mm][0], k0, a);
      a = mfma16(qf[mm][1], k1, a);
      sc[mm][ct] = a;
    }
  }
  __builtin_amdgcn_s_setprio(0);
  __syncthreads();  // B1: all K reads done

  // issue V stage into same region (arrival hidden under softmax)
  {
    const int c = t & 63;
#pragma unroll
    for (int it = 0; it < 8; it++) {
      int rr = it * 8 + w;
      gload_lds16(Yvt + vbase + (long)rr * 512 + ((c ^ (rr & 15)) * 8), kv + it * 4096 + w * 512);
    }
  }

  // bias gather + exp2 + partial row-sums
#pragma unroll
  for (int mm = 0; mm < 2; mm++) {
#pragma unroll
    for (int j = 0; j < 4; j++) {
      int lr = mm * 16 + g * 4 + j;
      int rowb = lr * 524;
      int a0 = rowb + 256 - (qb + lr) + w * 64 + l15;
      int lo = rowb, hi = rowb + 512;
      float s = 0.f;
#pragma unroll
      for (int ct = 0; ct < 4; ct++) {
        int idx = a0 + ct * 16;
        idx = idx < lo ? lo : idx;
        idx = idx > hi ? hi : idx;
        float p = exp2f(fmaf(sc[mm][ct][j], 0.18033688011112042f, b2f(buf[idx])));
        sc[mm][ct][j] = p;
        s += p;
      }
      for (int d = 1; d < 16; d <<= 1) s += __shfl_xor(s, d, 64);
      if (l15 == 0) redbuf[w][lr] = s;
    }
  }
  __syncthreads();  // B2: gathers done (drains V vmcnt), redbuf ready

  // probs into buf + rinv
#pragma unroll
  for (int mm = 0; mm < 2; mm++)
#pragma unroll
    for (int ct = 0; ct < 4; ct++) {
      int col = w * 64 + ct * 16 + l15;
#pragma unroll
      for (int j = 0; j < 4; j++)
        buf[(mm * 16 + g * 4 + j) * 524 + col] = f2b(sc[mm][ct][j]);
    }
  float rinv[2][4];
#pragma unroll
  for (int mm = 0; mm < 2; mm++)
#pragma unroll
    for (int j = 0; j < 4; j++) {
      int lr = mm * 16 + g * 4 + j;
      float s = 0.f;
#pragma unroll
      for (int ww = 0; ww < 8; ww++) s += redbuf[ww][lr];
      rinv[mm][j] = __builtin_amdgcn_rcpf(s);
    }
  __syncthreads();  // B3: probs visible, V staged

  // PV: wave = (mm = w>>2, dt = w&3): O[16 rows][16 d] from LDS V
  const int mm = w >> 2, dt = w & 3;
  const int dd = dt * 16 + l15;
  f4 accO = {};
  __builtin_amdgcn_s_setprio(1);
#pragma unroll
  for (int ks = 0; ks < 16; ks++) {
    union { uint2 u[2]; bh8 v; } pa;
    const unsigned short* pp = buf + (mm * 16 + l15) * 524 + ks * 32 + g8;
    pa.u[0] = *(const uint2*)(pp);
    pa.u[1] = *(const uint2*)(pp + 4);
    bh8 vb = *(const bh8*)(kv + dd * 512 + (((ks * 4 + g) ^ (dd & 15)) * 8));
    accO = mfma16(pa.v, vb, accO);
  }
  __builtin_amdgcn_s_setprio(0);
#pragma unroll
  for (int j = 0; j < 4; j++) {
    int row = qb + mm * 16 + g * 4 + j;
    outL[((long)(b * 512 + row)) * 512 + h * 64 + dt * 16 + l15] = f2b(accO[j] * rinv[mm][j]);
  }
}

// ============================ global attention v2 ============================
// Block = 32 q-rows, 8 waves (cols split 64/wave). Direct global K/V.
__global__ __launch_bounds__(512) void attn_glob_kern(
    const unsigned short* __restrict__ Yq, const unsigned short* __restrict__ Yk,
    const unsigned short* __restrict__ Yvt, unsigned short* __restrict__ outG) {
  __shared__ unsigned short buf[32 * 520];
  __shared__ float redbuf[8][32];

  const int t = threadIdx.x, lane = t & 63, w = t >> 6;
  const int l15 = lane & 15, g = lane >> 4, g8 = g * 8;
  int n = blockIdx.x;
  int bid = (n & 7) * 256 + (n >> 3);
  const int qt = bid & 15;
  const int hg = (bid >> 4) & 3;
  const int b = bid >> 6;
  const int qb = qt * 32;
  const long base = ((long)(b * 512)) * 1024 + 512 + hg * 128;

  bh8 qf[2][4];
#pragma unroll
  for (int mm = 0; mm < 2; mm++) {
    const unsigned short* qp = Yq + base + (long)(qb + mm * 16 + l15) * 1024 + g8;
#pragma unroll
    for (int ks = 0; ks < 4; ks++) qf[mm][ks] = *(const bh8*)(qp + ks * 32);
  }

  f4 sc[2][4];
  __builtin_amdgcn_s_setprio(1);
#pragma unroll
  for (int ct = 0; ct < 4; ct++) {
    int r = w * 64 + ct * 16 + l15;
    const unsigned short* kp = Yk + base + (long)r * 1024 + g8;
    bh8 kf[4];
#pragma unroll
    for (int ks = 0; ks < 4; ks++) kf[ks] = *(const bh8*)(kp + ks * 32);
#pragma unroll
    for (int mm = 0; mm < 2; mm++) {
      f4 a = {};
#pragma unroll
      for (int ks = 0; ks < 4; ks++) a = mfma16(qf[mm][ks], kf[ks], a);
      sc[mm][ct] = a;
    }
  }
  __builtin_amdgcn_s_setprio(0);

#pragma unroll
  for (int mm = 0; mm < 2; mm++) {
#pragma unroll
    for (int j = 0; j < 4; j++) {
      int lr = mm * 16 + g * 4 + j;
      float s = 0.f;
#pragma unroll
      for (int ct = 0; ct < 4; ct++) {
        float p = exp2f(sc[mm][ct][j] * 0.12751745334f);  // 1/sqrt(128)*log2(e)
        sc[mm][ct][j] = p;
        s += p;
      }
      for (int d = 1; d < 16; d <<= 1) s += __shfl_xor(s, d, 64);
      if (l15 == 0) redbuf[w][lr] = s;
    }
  }
#pragma unroll
  for (int mm = 0; mm < 2; mm++)
#pragma unroll
    for (int ct = 0; ct < 4; ct++) {
      int col = w * 64 + ct * 16 + l15;
#pragma unroll
      for (int j = 0; j < 4; j++)
        buf[(mm * 16 + g * 4 + j) * 520 + col] = f2b(sc[mm][ct][j]);
    }
  __syncthreads();  // probs + redbuf visible

  float rinv[2][4];
#pragma unroll
  for (int mm = 0; mm < 2; mm++)
#pragma unroll
    for (int j = 0; j < 4; j++) {
      int lr = mm * 16 + g * 4 + j;
      float s = 0.f;
#pragma unroll
      for (int ww = 0; ww < 8; ww++) s += redbuf[ww][lr];
      rinv[mm][j] = __builtin_amdgcn_rcpf(s);
    }

  // PV: wave w owns d-cols [w*16, +16), 2 m-tiles
  f4 accO[2] = {};
  const unsigned short* vr = Yvt + ((long)(b * 4 + hg) * 128 + w * 16 + l15) * 512;
  __builtin_amdgcn_s_setprio(1);
#pragma unroll
  for (int ks = 0; ks < 16; ks++) {
    bh8 vb = *(const bh8*)(vr + ks * 32 + g8);
#pragma unroll
    for (int mm = 0; mm < 2; mm++) {
      union { uint2 u[2]; bh8 v; } pa;
      const unsigned short* pp = buf + (mm * 16 + l15) * 520 + ks * 32 + g8;
      pa.u[0] = *(const uint2*)(pp);
      pa.u[1] = *(const uint2*)(pp + 4);
      accO[mm] = mfma16(pa.v, vb, accO[mm]);
    }
  }
  __builtin_amdgcn_s_setprio(0);
#pragma unroll
  for (int mm = 0; mm < 2; mm++)
#pragma unroll
    for (int j = 0; j < 4; j++) {
      int row = qb + mm * 16 + g * 4 + j;
      outG[((long)(b * 512 + row)) * 512 + hg * 128 + w * 16 + l15] = f2b(accO[mm][j] * rinv[mm][j]);
    }
}

// ============================ launch ============================
extern "C" void kernel_launch(void* const* d_in, const int* in_sizes, int n_in,
                              void* d_out, int out_size, void* d_ws, size_t ws_size,
                              hipStream_t stream) {
  const float* query = (const float*)d_in[0];
  const float* key   = (const float*)d_in[1];
  const float* value = (const float*)d_in[2];
  const float* wq = (const float*)d_in[3];   const float* bq = (const float*)d_in[4];
  const float* wk = (const float*)d_in[5];   const float* bk = (const float*)d_in[6];
  const float* wv = (const float*)d_in[7];   const float* bv = (const float*)d_in[8];
  const float* wo = (const float*)d_in[9];   const float* bo = (const float*)d_in[10];
  const float* rel_k = (const float*)d_in[11];
  const float* g_in_w = (const float*)d_in[12];  const float* g_in_b = (const float*)d_in[13];
  const float* g_out_w = (const float*)d_in[14]; const float* g_out_b = (const float*)d_in[15];

  unsigned short* p = (unsigned short*)d_ws;
  unsigned short* Xq = p;            p += 8388608;
  unsigned short* Xk = p;            p += 8388608;
  unsigned short* Xv = p;            p += 8388608;
  unsigned short* Yq = p;            p += 16777216;   // [16384][1024]
  unsigned short* Yk = p;            p += 16777216;
  unsigned short* Yvt_l = p;         p += 8388608;    // [b][h][64][512]
  unsigned short* Yvt_g = p;         p += 8388608;    // [b][hg][128][512]
  unsigned short* Wq = p;            p += 524288;
  unsigned short* Wk = p;            p += 524288;
  unsigned short* Wv = p;            p += 524288;
  unsigned short* Wgo = p;           p += 262144;
  unsigned short* Wo_ = p;           p += 262144;
  unsigned short* Rk = p;            p += 32832;
  unsigned short* localb = Xq;
  unsigned short* gattnb = Xk;
  unsigned short* comb   = Xv;

  prep_x_kern<<<8192, 256, 0, stream>>>(query, key, value, Xq, Xk, Xv);
  prep_w_kern<<<2081, 256, 0, stream>>>(wq, wk, wv, g_in_w, g_out_w, wo, rel_k,
                                        Wq, Wk, Wv, Wgo, Wo_, Rk);

  gemm_bf16_kern<8, 0><<<1024, 256, 0, stream>>>(Xq, Wq, bq, g_in_b, nullptr, Yq, nullptr, nullptr);
  gemm_bf16_kern<8, 0><<<1024, 256, 0, stream>>>(Xk, Wk, bk, g_in_b + 512, nullptr, Yk, nullptr, nullptr);
  gemm_bf16_kern<8, 3><<<1024, 256, 0, stream>>>(Xv, Wv, bv, g_in_b + 1024, nullptr, Yvt_l, Yvt_g, nullptr);

  attn_local_kern<<<4096, 512, 0, stream>>>(Yq, Yk, Yvt_l, Rk, localb);
  attn_glob_kern<<<2048, 512, 0, stream>>>(Yq, Yk, Yvt_g, gattnb);

  gemm_bf16_kern<4, 1><<<512, 256, 0, stream>>>(gattnb, Wgo, g_out_b, nullptr, localb, comb, nullptr, nullptr);
  gemm_bf16_kern<4, 2><<<512, 256, 0, stream>>>(comb, Wo_, bo, nullptr, nullptr, nullptr, nullptr, (float*)d_out);
}

// Round 5
// 335.402 us; speedup vs baseline: 1.4261x; 1.1445x over previous
//
#include <hip/hip_runtime.h>

typedef __attribute__((ext_vector_type(8))) short bh8;
typedef __attribute__((ext_vector_type(4))) float f4;

#define DEVI static __device__ __forceinline__

DEVI unsigned short f2b(float f) {
  union { float f; unsigned u; } v; v.f = f;
  unsigned r = v.u + 0x7fffu + ((v.u >> 16) & 1u);
  return (unsigned short)(r >> 16);
}
DEVI float b2f(unsigned short h) {
  union { unsigned u; float f; } v; v.u = ((unsigned)h) << 16;
  return v.f;
}
DEVI f4 mfma16(bh8 a, bh8 b, f4 c) {
  return __builtin_amdgcn_mfma_f32_16x16x32_bf16(a, b, c, 0, 0, 0);
}
DEVI void gload_lds16(const unsigned short* g, unsigned short* l) {
  __builtin_amdgcn_global_load_lds(
      (const __attribute__((address_space(1))) void*)(g),
      (__attribute__((address_space(3))) void*)(l), 16, 0, 0);
}

// ============================ prep kernels ============================
__global__ __launch_bounds__(256) void prep_x_kern(
    const float* __restrict__ q, const float* __restrict__ k, const float* __restrict__ v,
    unsigned short* __restrict__ xq, unsigned short* __restrict__ xk, unsigned short* __restrict__ xv) {
  long i = ((long)blockIdx.x * 256 + threadIdx.x) * 4;
  if (i >= 8388608L) return;
  float4 a = *(const float4*)(q + i);
  float4 b = *(const float4*)(k + i);
  float4 c = *(const float4*)(v + i);
  union { unsigned short s[4]; uint2 u; } pa, pb, pc;
  pa.s[0] = f2b(a.x); pa.s[1] = f2b(a.y); pa.s[2] = f2b(a.z); pa.s[3] = f2b(a.w);
  pb.s[0] = f2b(b.x); pb.s[1] = f2b(b.y); pb.s[2] = f2b(b.z); pb.s[3] = f2b(b.w);
  pc.s[0] = f2b(c.x); pc.s[1] = f2b(c.y); pc.s[2] = f2b(c.z); pc.s[3] = f2b(c.w);
  *(uint2*)(xq + i) = pa.u;
  *(uint2*)(xk + i) = pb.u;
  *(uint2*)(xv + i) = pc.u;
}

__global__ __launch_bounds__(256) void prep_w_kern(
    const float* __restrict__ wq, const float* __restrict__ wk, const float* __restrict__ wv,
    const float* __restrict__ g_in_w, const float* __restrict__ g_out_w,
    const float* __restrict__ wo, const float* __restrict__ rel_k,
    unsigned short* __restrict__ Wq, unsigned short* __restrict__ Wk, unsigned short* __restrict__ Wv,
    unsigned short* __restrict__ Wgo, unsigned short* __restrict__ Wo_, unsigned short* __restrict__ Rk) {
  long i = ((long)blockIdx.x * 256 + threadIdx.x) * 4;
  if (i >= 2129984L) return;
  const float* src; unsigned short* dst; long off;
  if (i < 524288L)        { dst = Wq;  off = i; src = (i < 262144L) ? wq + i : g_in_w + (i - 262144L); }
  else if (i < 1048576L)  { long j = i - 524288L;  dst = Wk;  off = j; src = (j < 262144L) ? wk + j : g_in_w + j; }
  else if (i < 1572864L)  { long j = i - 1048576L; dst = Wv;  off = j; src = (j < 262144L) ? wv + j : g_in_w + 262144L + j; }
  else if (i < 1835008L)  { long j = i - 1572864L; dst = Wgo; off = j; src = g_out_w + j; }
  else if (i < 2097152L)  { long j = i - 1835008L; dst = Wo_; off = j; src = wo + j; }
  else                    { long j = i - 2097152L; dst = Rk;  off = j; src = rel_k + j; }
  float4 f = *(const float4*)src;
  union { unsigned short s[4]; uint2 u; } p;
  p.s[0] = f2b(f.x); p.s[1] = f2b(f.y); p.s[2] = f2b(f.z); p.s[3] = f2b(f.w);
  *(uint2*)(dst + off) = p.u;
}

// ============================ GEMM (R2 form) ============================
template <int NB, int EPI>
__global__ __launch_bounds__(256) void gemm_bf16_kern(
    const unsigned short* __restrict__ A, const unsigned short* __restrict__ Bw,
    const float* __restrict__ bias0, const float* __restrict__ bias1,
    const unsigned short* __restrict__ aux,
    unsigned short* __restrict__ outb, unsigned short* __restrict__ outb2,
    float* __restrict__ outf) {
  __shared__ unsigned short lsA[128 * 32];
  __shared__ unsigned short lsB[128 * 32];
  const int t = threadIdx.x;
  const int lane = t & 63, w = t >> 6;
  const int l15 = lane & 15, g8 = (lane >> 4) * 8, g4 = (lane >> 4) * 4;
  int n = blockIdx.x;
  int x = n >> 3, c = n & 7;
  const int rb = (c * 16 + (x & 15)) * 128;
  const int cb = (x >> 4) * 128;
  const int wr = (w >> 1) * 64, wc = (w & 1) * 64;
  const int e0 = t * 8, e1 = 2048 + t * 8;
  const int r0 = e0 >> 5, k0i = e0 & 31;
  const int r1 = e1 >> 5, k1i = e1 & 31;

  const unsigned short* pa0 = A + (long)(rb + r0) * 512 + k0i;
  const unsigned short* pa1 = A + (long)(rb + r1) * 512 + k1i;
  const unsigned short* pb0 = Bw + (long)(cb + r0) * 512 + k0i;
  const unsigned short* pb1 = Bw + (long)(cb + r1) * 512 + k1i;
  unsigned short* dA0 = lsA + w * 512;
  unsigned short* dA1 = lsA + 2048 + w * 512;
  unsigned short* dB0 = lsB + w * 512;
  unsigned short* dB1 = lsB + 2048 + w * 512;

  f4 acc[4][4] = {};
  for (int k0 = 0; k0 < 512; k0 += 32) {
    __syncthreads();
    gload_lds16(pa0 + k0, dA0);
    gload_lds16(pa1 + k0, dA1);
    gload_lds16(pb0 + k0, dB0);
    gload_lds16(pb1 + k0, dB1);
    __syncthreads();
    bh8 af[4], bf[4];
#pragma unroll
    for (int m = 0; m < 4; m++) af[m] = *(const bh8*)(lsA + (wr + m * 16 + l15) * 32 + g8);
#pragma unroll
    for (int nn = 0; nn < 4; nn++) bf[nn] = *(const bh8*)(lsB + (wc + nn * 16 + l15) * 32 + g8);
#pragma unroll
    for (int m = 0; m < 4; m++)
#pragma unroll
      for (int nn = 0; nn < 4; nn++)
        acc[m][nn] = mfma16(af[m], bf[nn], acc[m][nn]);
  }
#pragma unroll
  for (int m = 0; m < 4; m++) {
#pragma unroll
    for (int nn = 0; nn < 4; nn++) {
#pragma unroll
      for (int j = 0; j < 4; j++) {
        int row = rb + wr + m * 16 + g4 + j;
        int col = cb + wc + nn * 16 + l15;
        float v = acc[m][nn][j];
        if constexpr (EPI == 0) {
          v += (col < 512) ? bias0[col] : bias1[col - 512];
          outb[(long)row * (NB * 128) + col] = f2b(v);
        } else if constexpr (EPI == 3) {
          v += (col < 512) ? bias0[col] : bias1[col - 512];
          int b = row >> 9, s = row & 511;
          if (col < 512) {
            int h = col >> 6, d = col & 63;
            outb[(((long)(b * 8 + h) * 64 + d) << 9) + s] = f2b(v);
          } else {
            int c2 = col - 512, hg = c2 >> 7, dg = c2 & 127;
            outb2[(((long)(b * 4 + hg) * 128 + dg) << 9) + s] = f2b(v);
          }
        } else if constexpr (EPI == 1) {
          v += bias0[col];
          float cv = 0.7f * b2f(aux[(long)row * 512 + col]) + 0.3f * v;
          outb[(long)row * 512 + col] = f2b(cv);
        } else {
          v += bias0[col];
          outf[(long)row * 512 + col] = v;
        }
      }
    }
  }
}

// ============================ local attention v4 ============================
// Block = 32 q-rows, 8 waves. One 32KB chunk buffer cycles through
// K[0:256] -> K[256:512] -> V[:, 0:256] -> V[:, 256:512]; staging of each
// chunk overlaps compute on the previous one. LDS ~66KB -> 2 blocks/CU.
__global__ __launch_bounds__(512, 4) void attn_local_kern(
    const unsigned short* __restrict__ Yq, const unsigned short* __restrict__ Yk,
    const unsigned short* __restrict__ Yvt, const unsigned short* __restrict__ relk,
    unsigned short* __restrict__ outL) {
  __shared__ unsigned short kv[16384];      // 32KB chunk
  __shared__ unsigned short buf[32 * 524];  // qrel then probs
  __shared__ float redbuf[8][32];

  const int t = threadIdx.x, lane = t & 63, w = t >> 6;
  const int l15 = lane & 15, g = lane >> 4, g8 = g * 8;
  int n = blockIdx.x;
  int bid = (n & 7) * 512 + (n >> 3);       // XCD swizzle
  const int qt = bid & 15;
  const int h = (bid >> 4) & 7;
  const int b = bid >> 7;
  const int qb = qt * 32;
  const long base = ((long)(b * 512)) * 1024 + h * 64;
  const long vbase = ((long)(b * 8 + h)) * 64 * 512;

  // K chunk: slot s=it*512+t -> local row r=s>>3 (0..255), chunk c=s&7.
  // slot c holds global chunk c^(r&7); dest wave-linear.
#define STAGE_K(ROFF) { \
    const int c_ = t & 7; \
    _Pragma("unroll") \
    for (int it = 0; it < 4; it++) { \
      int rr = it * 64 + (t >> 3); \
      gload_lds16(Yk + base + (long)((ROFF) + rr) * 1024 + ((c_ ^ (rr & 7)) * 8), \
                  kv + it * 4096 + w * 512); \
    } }
  // V chunk: slot s=it*512+t -> d=s>>5 (0..63), chunk c=s&31 (k-cols COFF+256).
#define STAGE_V(COFF) { \
    const int c_ = t & 31; \
    _Pragma("unroll") \
    for (int it = 0; it < 4; it++) { \
      int dd_ = it * 16 + (t >> 5); \
      gload_lds16(Yvt + vbase + (long)dd_ * 512 + (COFF) + ((c_ ^ (dd_ & 15)) * 8), \
                  kv + it * 4096 + w * 512); \
    } }

  STAGE_K(0);

  // Q fragments: 2 m-tiles
  bh8 qf[2][2];
#pragma unroll
  for (int mm = 0; mm < 2; mm++) {
    const unsigned short* qp = Yq + base + (long)(qb + mm * 16 + l15) * 1024 + g8;
    qf[mm][0] = *(const bh8*)(qp);
    qf[mm][1] = *(const bh8*)(qp + 32);
  }

  // qrel = (Q @ relk^T)*LOG2E -> buf[32][524]   (overlaps K0 staging)
  for (int tt = w; tt < 33; tt += 8) {
    int ri = tt * 16 + l15; if (ri > 512) ri = 512;
    const unsigned short* rp = relk + ri * 64 + g8;
    bh8 rf0 = *(const bh8*)(rp), rf1 = *(const bh8*)(rp + 32);
    int col = tt * 16 + l15;
#pragma unroll
    for (int mm = 0; mm < 2; mm++) {
      f4 a = {};
      a = mfma16(qf[mm][0], rf0, a);
      a = mfma16(qf[mm][1], rf1, a);
      if (col < 524) {
#pragma unroll
        for (int j = 0; j < 4; j++)
          buf[(mm * 16 + g * 4 + j) * 524 + col] = f2b(a[j] * 1.4426950408889634f);
      }
    }
  }
  __syncthreads();  // B0: K0 staged + qrel visible

  f4 sc[2][4];
  float rs[2][4] = {};

  // QK0: wave w -> local k-rows w*32 + ct*16 + l15 (cols 0..255)
  __builtin_amdgcn_s_setprio(1);
#pragma unroll
  for (int ct = 0; ct < 2; ct++) {
    int rl = w * 32 + ct * 16 + l15;
    bh8 k0 = *(const bh8*)(kv + rl * 64 + ((g ^ (rl & 7)) * 8));
    bh8 k1 = *(const bh8*)(kv + rl * 64 + (((g + 4) ^ (rl & 7)) * 8));
#pragma unroll
    for (int mm = 0; mm < 2; mm++) {
      f4 a = {};
      a = mfma16(qf[mm][0], k0, a);
      a = mfma16(qf[mm][1], k1, a);
      sc[mm][ct] = a;
    }
  }
  __builtin_amdgcn_s_setprio(0);
  __syncthreads();  // B1: K0 reads done

  STAGE_K(256);

  // gather+exp half 0 (cols 0..255) — overlaps K1 flight
#pragma unroll
  for (int mm = 0; mm < 2; mm++)
#pragma unroll
    for (int j = 0; j < 4; j++) {
      int lr = mm * 16 + g * 4 + j;
      int rowb = lr * 524;
      int a0 = rowb + 256 - (qb + lr) + w * 32 + l15;
      int lo = rowb, hi = rowb + 512;
#pragma unroll
      for (int ct = 0; ct < 2; ct++) {
        int idx = a0 + ct * 16;
        idx = idx < lo ? lo : idx;
        idx = idx > hi ? hi : idx;
        float p = exp2f(fmaf(sc[mm][ct][j], 0.18033688011112042f, b2f(buf[idx])));
        sc[mm][ct][j] = p;
        rs[mm][j] += p;
      }
    }
  __syncthreads();  // B2: K1 staged

  // QK1 (cols 256..511)
  __builtin_amdgcn_s_setprio(1);
#pragma unroll
  for (int ct = 0; ct < 2; ct++) {
    int rl = w * 32 + ct * 16 + l15;
    bh8 k0 = *(const bh8*)(kv + rl * 64 + ((g ^ (rl & 7)) * 8));
    bh8 k1 = *(const bh8*)(kv + rl * 64 + (((g + 4) ^ (rl & 7)) * 8));
#pragma unroll
    for (int mm = 0; mm < 2; mm++) {
      f4 a = {};
      a = mfma16(qf[mm][0], k0, a);
      a = mfma16(qf[mm][1], k1, a);
      sc[mm][2 + ct] = a;
    }
  }
  __builtin_amdgcn_s_setprio(0);
  __syncthreads();  // B3: K1 reads done

  STAGE_V(0);

  // gather+exp half 1 + row sums — overlaps V0 flight
#pragma unroll
  for (int mm = 0; mm < 2; mm++)
#pragma unroll
    for (int j = 0; j < 4; j++) {
      int lr = mm * 16 + g * 4 + j;
      int rowb = lr * 524;
      int a0 = rowb + 256 - (qb + lr) + 256 + w * 32 + l15;
      int lo = rowb, hi = rowb + 512;
#pragma unroll
      for (int ct = 0; ct < 2; ct++) {
        int idx = a0 + ct * 16;
        idx = idx < lo ? lo : idx;
        idx = idx > hi ? hi : idx;
        float p = exp2f(fmaf(sc[mm][2 + ct][j], 0.18033688011112042f, b2f(buf[idx])));
        sc[mm][2 + ct][j] = p;
        rs[mm][j] += p;
      }
      float s = rs[mm][j];
      for (int d = 1; d < 16; d <<= 1) s += __shfl_xor(s, d, 64);
      if (l15 == 0) redbuf[w][lr] = s;
    }
  __syncthreads();  // B4: all qrel gathers done, V0 staged, redbuf visible

  // probs into buf (overwrites qrel) + rinv
#pragma unroll
  for (int mm = 0; mm < 2; mm++)
#pragma unroll
    for (int ct4 = 0; ct4 < 4; ct4++) {
      int col = (ct4 >> 1) * 256 + w * 32 + (ct4 & 1) * 16 + l15;
#pragma unroll
      for (int j = 0; j < 4; j++)
        buf[(mm * 16 + g * 4 + j) * 524 + col] = f2b(sc[mm][ct4][j]);
    }
  float rinv[2][4];
#pragma unroll
  for (int mm = 0; mm < 2; mm++)
#pragma unroll
    for (int j = 0; j < 4; j++) {
      int lr = mm * 16 + g * 4 + j;
      float s = 0.f;
#pragma unroll
      for (int ww = 0; ww < 8; ww++) s += redbuf[ww][lr];
      rinv[mm][j] = __builtin_amdgcn_rcpf(s);
    }
  __syncthreads();  // B5: probs visible (V0 already staged)

  // PV0: ks 0..7 from V0 [64][256]
  const int mmw = w >> 2, dt = w & 3;
  const int dd = dt * 16 + l15;
  f4 accO = {};
  __builtin_amdgcn_s_setprio(1);
#pragma unroll
  for (int ks = 0; ks < 8; ks++) {
    union { uint2 u[2]; bh8 v; } pa;
    const unsigned short* pp = buf + (mmw * 16 + l15) * 524 + ks * 32 + g8;
    pa.u[0] = *(const uint2*)(pp);
    pa.u[1] = *(const uint2*)(pp + 4);
    bh8 vb = *(const bh8*)(kv + dd * 256 + (((ks * 4 + g) ^ (dd & 15)) * 8));
    accO = mfma16(pa.v, vb, accO);
  }
  __builtin_amdgcn_s_setprio(0);
  __syncthreads();  // B6: V0 reads done

  STAGE_V(256);
  __syncthreads();  // B7: V1 staged

  // PV1: ks 8..15 from V1
  __builtin_amdgcn_s_setprio(1);
#pragma unroll
  for (int ks = 8; ks < 16; ks++) {
    union { uint2 u[2]; bh8 v; } pa;
    const unsigned short* pp = buf + (mmw * 16 + l15) * 524 + ks * 32 + g8;
    pa.u[0] = *(const uint2*)(pp);
    pa.u[1] = *(const uint2*)(pp + 4);
    bh8 vb = *(const bh8*)(kv + dd * 256 + ((((ks - 8) * 4 + g) ^ (dd & 15)) * 8));
    accO = mfma16(pa.v, vb, accO);
  }
  __builtin_amdgcn_s_setprio(0);
#pragma unroll
  for (int j = 0; j < 4; j++) {
    int row = qb + mmw * 16 + g * 4 + j;
    outL[((long)(b * 512 + row)) * 512 + h * 64 + dt * 16 + l15] = f2b(accO[j] * rinv[mmw][j]);
  }
#undef STAGE_K
#undef STAGE_V
}

// ============================ global attention v2 ============================
__global__ __launch_bounds__(512) void attn_glob_kern(
    const unsigned short* __restrict__ Yq, const unsigned short* __restrict__ Yk,
    const unsigned short* __restrict__ Yvt, unsigned short* __restrict__ outG) {
  __shared__ unsigned short buf[32 * 520];
  __shared__ float redbuf[8][32];

  const int t = threadIdx.x, lane = t & 63, w = t >> 6;
  const int l15 = lane & 15, g = lane >> 4, g8 = g * 8;
  int n = blockIdx.x;
  int bid = (n & 7) * 256 + (n >> 3);
  const int qt = bid & 15;
  const int hg = (bid >> 4) & 3;
  const int b = bid >> 6;
  const int qb = qt * 32;
  const long base = ((long)(b * 512)) * 1024 + 512 + hg * 128;

  bh8 qf[2][4];
#pragma unroll
  for (int mm = 0; mm < 2; mm++) {
    const unsigned short* qp = Yq + base + (long)(qb + mm * 16 + l15) * 1024 + g8;
#pragma unroll
    for (int ks = 0; ks < 4; ks++) qf[mm][ks] = *(const bh8*)(qp + ks * 32);
  }

  f4 sc[2][4];
  __builtin_amdgcn_s_setprio(1);
#pragma unroll
  for (int ct = 0; ct < 4; ct++) {
    int r = w * 64 + ct * 16 + l15;
    const unsigned short* kp = Yk + base + (long)r * 1024 + g8;
    bh8 kf[4];
#pragma unroll
    for (int ks = 0; ks < 4; ks++) kf[ks] = *(const bh8*)(kp + ks * 32);
#pragma unroll
    for (int mm = 0; mm < 2; mm++) {
      f4 a = {};
#pragma unroll
      for (int ks = 0; ks < 4; ks++) a = mfma16(qf[mm][ks], kf[ks], a);
      sc[mm][ct] = a;
    }
  }
  __builtin_amdgcn_s_setprio(0);

#pragma unroll
  for (int mm = 0; mm < 2; mm++) {
#pragma unroll
    for (int j = 0; j < 4; j++) {
      int lr = mm * 16 + g * 4 + j;
      float s = 0.f;
#pragma unroll
      for (int ct = 0; ct < 4; ct++) {
        float p = exp2f(sc[mm][ct][j] * 0.12751745334f);  // 1/sqrt(128)*log2(e)
        sc[mm][ct][j] = p;
        s += p;
      }
      for (int d = 1; d < 16; d <<= 1) s += __shfl_xor(s, d, 64);
      if (l15 == 0) redbuf[w][lr] = s;
    }
  }
#pragma unroll
  for (int mm = 0; mm < 2; mm++)
#pragma unroll
    for (int ct = 0; ct < 4; ct++) {
      int col = w * 64 + ct * 16 + l15;
#pragma unroll
      for (int j = 0; j < 4; j++)
        buf[(mm * 16 + g * 4 + j) * 520 + col] = f2b(sc[mm][ct][j]);
    }
  __syncthreads();  // probs + redbuf visible

  float rinv[2][4];
#pragma unroll
  for (int mm = 0; mm < 2; mm++)
#pragma unroll
    for (int j = 0; j < 4; j++) {
      int lr = mm * 16 + g * 4 + j;
      float s = 0.f;
#pragma unroll
      for (int ww = 0; ww < 8; ww++) s += redbuf[ww][lr];
      rinv[mm][j] = __builtin_amdgcn_rcpf(s);
    }

  // PV: wave w owns d-cols [w*16, +16), 2 m-tiles
  f4 accO[2] = {};
  const unsigned short* vr = Yvt + ((long)(b * 4 + hg) * 128 + w * 16 + l15) * 512;
  __builtin_amdgcn_s_setprio(1);
#pragma unroll
  for (int ks = 0; ks < 16; ks++) {
    bh8 vb = *(const bh8*)(vr + ks * 32 + g8);
#pragma unroll
    for (int mm = 0; mm < 2; mm++) {
      union { uint2 u[2]; bh8 v; } pa;
      const unsigned short* pp = buf + (mm * 16 + l15) * 520 + ks * 32 + g8;
      pa.u[0] = *(const uint2*)(pp);
      pa.u[1] = *(const uint2*)(pp + 4);
      accO[mm] = mfma16(pa.v, vb, accO[mm]);
    }
  }
  __builtin_amdgcn_s_setprio(0);
#pragma unroll
  for (int mm = 0; mm < 2; mm++)
#pragma unroll
    for (int j = 0; j < 4; j++) {
      int row = qb + mm * 16 + g * 4 + j;
      outG[((long)(b * 512 + row)) * 512 + hg * 128 + w * 16 + l15] = f2b(accO[mm][j] * rinv[mm][j]);
    }
}

// ============================ launch ============================
extern "C" void kernel_launch(void* const* d_in, const int* in_sizes, int n_in,
                              void* d_out, int out_size, void* d_ws, size_t ws_size,
                              hipStream_t stream) {
  const float* query = (const float*)d_in[0];
  const float* key   = (const float*)d_in[1];
  const float* value = (const float*)d_in[2];
  const float* wq = (const float*)d_in[3];   const float* bq = (const float*)d_in[4];
  const float* wk = (const float*)d_in[5];   const float* bk = (const float*)d_in[6];
  const float* wv = (const float*)d_in[7];   const float* bv = (const float*)d_in[8];
  const float* wo = (const float*)d_in[9];   const float* bo = (const float*)d_in[10];
  const float* rel_k = (const float*)d_in[11];
  const float* g_in_w = (const float*)d_in[12];  const float* g_in_b = (const float*)d_in[13];
  const float* g_out_w = (const float*)d_in[14]; const float* g_out_b = (const float*)d_in[15];

  unsigned short* p = (unsigned short*)d_ws;
  unsigned short* Xq = p;            p += 8388608;
  unsigned short* Xk = p;            p += 8388608;
  unsigned short* Xv = p;            p += 8388608;
  unsigned short* Yq = p;            p += 16777216;   // [16384][1024]
  unsigned short* Yk = p;            p += 16777216;
  unsigned short* Yvt_l = p;         p += 8388608;    // [b][h][64][512]
  unsigned short* Yvt_g = p;         p += 8388608;    // [b][hg][128][512]
  unsigned short* Wq = p;            p += 524288;
  unsigned short* Wk = p;            p += 524288;
  unsigned short* Wv = p;            p += 524288;
  unsigned short* Wgo = p;           p += 262144;
  unsigned short* Wo_ = p;           p += 262144;
  unsigned short* Rk = p;            p += 32832;
  unsigned short* localb = Xq;
  unsigned short* gattnb = Xk;
  unsigned short* comb   = Xv;

  prep_x_kern<<<8192, 256, 0, stream>>>(query, key, value, Xq, Xk, Xv);
  prep_w_kern<<<2081, 256, 0, stream>>>(wq, wk, wv, g_in_w, g_out_w, wo, rel_k,
                                        Wq, Wk, Wv, Wgo, Wo_, Rk);

  gemm_bf16_kern<8, 0><<<1024, 256, 0, stream>>>(Xq, Wq, bq, g_in_b, nullptr, Yq, nullptr, nullptr);
  gemm_bf16_kern<8, 0><<<1024, 256, 0, stream>>>(Xk, Wk, bk, g_in_b + 512, nullptr, Yk, nullptr, nullptr);
  gemm_bf16_kern<8, 3><<<1024, 256, 0, stream>>>(Xv, Wv, bv, g_in_b + 1024, nullptr, Yvt_l, Yvt_g, nullptr);

  attn_local_kern<<<4096, 512, 0, stream>>>(Yq, Yk, Yvt_l, Rk, localb);
  attn_glob_kern<<<2048, 512, 0, stream>>>(Yq, Yk, Yvt_g, gattnb);

  gemm_bf16_kern<4, 1><<<512, 256, 0, stream>>>(gattnb, Wgo, g_out_b, nullptr, localb, comb, nullptr, nullptr);
  gemm_bf16_kern<4, 2><<<512, 256, 0, stream>>>(comb, Wo_, bo, nullptr, nullptr, nullptr, nullptr, (float*)d_out);
}